// Round 7
// baseline (650.588 us; speedup 1.0000x reference)
//
#include <hip/hip_runtime.h>
#include <hip/hip_fp16.h>

// Mean aggregation: out[b,:] = (1/K) * sum_k embed[idx[b,k],:]
// B=100000, K=32, N=500000, D=128 fp32.
//
// R9 (resubmit after infra failure; source unchanged):
// TWO rows per gather instruction.
// Evidence: R6 (fp16, 3.2M loads x 2 lines) == R8 (int8, 3.2M loads x 1
// line) == ~232 us/iter, while R3 (3.2M loads x 4 lines) was line-bound at
// 49 G lines/s. => gather obeys  time = max(lines/49G, loads * ~30cy/CU):
// a random wave-load costs ~30 cyc of per-CU miss handling regardless of
// line count (1-2). Halving LINES (R8) did nothing; the lever is halving
// INSTRUCTIONS.
// Fix: int8 row = 128 B = 32 lanes x 4 B, so one 64-lane dword load
// fetches TWO rows (lower half -> row 2j, upper half -> row 2j+1):
// 3.2M -> 1.6M gather instructions, same line count. Each lane dequants
// 4 columns; per-half scale via two readlane'd SGPRs + cndmask; final
// cross-half combine with one shfl_xor(32) per accumulator; all 64 lanes
// store 8 B (contiguous 512 B row).
// Quant pass unchanged from R8 (isolates the delta to the gather).

constexpr int K = 32;
constexpr int D = 128;
constexpr int WAVES_PER_BLOCK = 4;
constexpr int BLOCK = WAVES_PER_BLOCK * 64;  // 256

typedef float vfloat2 __attribute__((ext_vector_type(2)));
typedef float vfloat4 __attribute__((ext_vector_type(4)));

__device__ __forceinline__ float readlane_f32(float v, int lane) {
    union { float f; int i; } u;
    u.f = v;
    u.i = __builtin_amdgcn_readlane(u.i, lane);
    return u.f;
}

__device__ __forceinline__ float shflxor32_f32(float v) {
    union { float f; int i; } u;
    u.f = v;
    u.i = __shfl_xor(u.i, 32);
    return u.f;
}

// ---------- fp32 -> int8+fp16scale conversion: 2 rows per wave ----------
__global__ __launch_bounds__(256)
void quant_kernel(const float* __restrict__ src,
                  unsigned int* __restrict__ tab32,   // packed int8 quads
                  __half* __restrict__ hscale,
                  int N) {
    const int lane = threadIdx.x & 63;
    const int sub  = lane & 31;                 // chunk within the row
    const int wid  = (blockIdx.x * BLOCK + threadIdx.x) >> 6;
    int row = wid * 2 + (lane >> 5);            // 2 rows per wave
    const bool live = row < N;
    if (row >= N) row = N - 1;                  // clamp: safe load, no store

    // Sequential 16 B/lane NT read (read-once stream; don't evict the
    // int8 table we're building).
    const vfloat4* rp = (const vfloat4*)(src + (size_t)row * D);
    vfloat4 v = __builtin_nontemporal_load(rp + sub);

    float m = fmaxf(fmaxf(fabsf(v.x), fabsf(v.y)),
                    fmaxf(fabsf(v.z), fabsf(v.w)));
#pragma unroll
    for (int off = 16; off; off >>= 1)          // reduce within 32-lane half
        m = fmaxf(m, __shfl_xor(m, off));
    m = fmaxf(m, 1e-20f);

    const float inv = 127.0f / m;
    const int qx = (int)rintf(v.x * inv);
    const int qy = (int)rintf(v.y * inv);
    const int qz = (int)rintf(v.z * inv);
    const int qw = (int)rintf(v.w * inv);
    const unsigned int pack = (unsigned)(qx & 0xff)
                            | ((unsigned)(qy & 0xff) << 8)
                            | ((unsigned)(qz & 0xff) << 16)
                            | ((unsigned)(qw & 0xff) << 24);

    if (live) {
        // int8 row = 128 B = one cache line; 32 lanes x 4 B contiguous.
        tab32[(size_t)row * (D / 4) + sub] = pack;
        if (sub == 0) hscale[row] = __float2half_rn(m * (1.0f / 127.0f));
    }
}

// ---------- int8 gather-mean, 2 rows per wave-load ----------
__global__ __launch_bounds__(BLOCK, 8)
void mean_agg_q2_kernel(const unsigned int* __restrict__ tab32,
                        const __half* __restrict__ hscale,
                        const int* __restrict__ idx,
                        float* __restrict__ out,
                        int B) {
    const int tid  = threadIdx.x;
    const int lane = tid & 63;
    const int sub  = lane & 31;             // dword slot within a row
    const int half = lane >> 5;             // 0: row 2j, 1: row 2j+1

    int b = blockIdx.x * WAVES_PER_BLOCK + (tid >> 6);
    b = __builtin_amdgcn_readfirstlane(b);  // wave-uniform node id
    if (b >= B) return;

    // Wave-uniform index pointer -> scalar (s_load) reads into SGPRs.
    const int* __restrict__ idx_b = idx + (size_t)b * K;
    int rows[K];
#pragma unroll
    for (int k = 0; k < K; ++k) {
        rows[k] = idx_b[k];
    }

    // All 32 per-row scales in ONE vector gather (lane k -> scale of row
    // k for k<32, mirrored in the upper half). 1 MB fp16 table is L2-hot.
    const int myrow = idx_b[sub];
    const float s_lane = __half2float(hscale[(unsigned)myrow]);

    // acc[c]: this lane's partial sum for column 4*sub + c, over the 16
    // rows its half handles.
    float acc[4] = {0.f, 0.f, 0.f, 0.f};

    // 16 wave-loads fetch all 32 rows (2 rows per load: 64 lanes x 4 B =
    // 256 B = 2 lines; lower half reads row 2j, upper half row 2j+1).
    unsigned int v[16];
#pragma unroll
    for (int j = 0; j < 16; ++j) {
        const unsigned r = (unsigned)((half == 0) ? rows[2 * j]
                                                  : rows[2 * j + 1]);
        v[j] = tab32[(size_t)r * (D / 4) + sub];
    }

#pragma unroll
    for (int j = 0; j < 16; ++j) {
        const float slo = readlane_f32(s_lane, 2 * j);      // scale row 2j
        const float shi = readlane_f32(s_lane, 2 * j + 1);  // scale row 2j+1
        const float sj = (half == 0) ? slo : shi;
        const unsigned int u = v[j];
        acc[0] += sj * (float)(int)(signed char)(u & 0xff);
        acc[1] += sj * (float)(int)(signed char)((u >> 8) & 0xff);
        acc[2] += sj * (float)(int)(signed char)((u >> 16) & 0xff);
        acc[3] += sj * (float)(int)(signed char)((u >> 24) & 0xff);
    }

    // Combine the two halves: lane L and L^32 hold partial sums for the
    // SAME 4 columns (rows even/odd split). One shfl_xor(32) each.
    const float inv = 1.0f / (float)K;
#pragma unroll
    for (int c = 0; c < 4; ++c) {
        acc[c] = (acc[c] + shflxor32_f32(acc[c])) * inv;
    }

    // Store: all 64 lanes write 8 B. Lane (sub, half) covers columns
    // 4*sub + 2*half + {0,1}; together: contiguous 512 B row.
    vfloat2 r;
    r.x = acc[2 * half];
    r.y = acc[2 * half + 1];
    vfloat2* op = (vfloat2*)(out + (size_t)b * D + 4 * sub + 2 * half);
    __builtin_nontemporal_store(r, op);
}

// ---------- fp32 fallback (proven R3 kernel) if ws too small ----------
__global__ __launch_bounds__(BLOCK, 8)
void mean_agg_kernel(const float* __restrict__ embed,
                     const int* __restrict__ idx,
                     float* __restrict__ out,
                     int B) {
    const int tid  = threadIdx.x;
    const int lane = tid & 63;

    int b = blockIdx.x * WAVES_PER_BLOCK + (tid >> 6);
    b = __builtin_amdgcn_readfirstlane(b);
    if (b >= B) return;

    const int* __restrict__ idx_b = idx + (size_t)b * K;
    int rows[K];
#pragma unroll
    for (int k = 0; k < K; ++k) rows[k] = idx_b[k];

    float2 acc[4];
    acc[0] = acc[1] = acc[2] = acc[3] = make_float2(0.f, 0.f);

#pragma unroll
    for (int kk = 0; kk < K; kk += 8) {
        float2 v[8];
#pragma unroll
        for (int j = 0; j < 8; ++j) {
            const float2* __restrict__ rp =
                (const float2*)(embed + (size_t)(unsigned)rows[kk + j] * D);
            v[j] = rp[lane];
        }
#pragma unroll
        for (int j = 0; j < 8; ++j) {
            acc[j & 3].x += v[j].x;
            acc[j & 3].y += v[j].y;
        }
    }

    const float inv = 1.0f / (float)K;
    vfloat2 r;
    r.x = (acc[0].x + acc[1].x + acc[2].x + acc[3].x) * inv;
    r.y = (acc[0].y + acc[1].y + acc[2].y + acc[3].y) * inv;

    vfloat2* op = (vfloat2*)(out + (size_t)b * D) + lane;
    __builtin_nontemporal_store(r, op);
}

extern "C" void kernel_launch(void* const* d_in, const int* in_sizes, int n_in,
                              void* d_out, int out_size, void* d_ws, size_t ws_size,
                              hipStream_t stream) {
    const float* embed = (const float*)d_in[0];
    const int*   idx   = (const int*)d_in[1];
    float* out = (float*)d_out;

    const int B = in_sizes[1] / K;                 // in_sizes are element counts
    const size_t n_elems = (size_t)in_sizes[0];    // N * D fp32 elements
    const int N = (int)(n_elems / D);              // table rows

    // Workspace layout: [hscale: N halfs, 256B-padded][int8 table: N*D bytes]
    const size_t scale_off = 256;
    const size_t scale_bytes = ((size_t)N * sizeof(__half) + 255) & ~(size_t)255;
    const size_t tab_off = scale_off + scale_bytes;
    const size_t need = tab_off + n_elems;         // 1 byte per element

    dim3 grid((B + WAVES_PER_BLOCK - 1) / WAVES_PER_BLOCK);

    if (d_ws != nullptr && ws_size >= need) {
        __half* hscale = (__half*)((char*)d_ws + scale_off);
        unsigned int* tab32 = (unsigned int*)((char*)d_ws + tab_off);

        const int rows_per_block = WAVES_PER_BLOCK * 2;   // 2 rows per wave
        dim3 qgrid((N + rows_per_block - 1) / rows_per_block);
        quant_kernel<<<qgrid, BLOCK, 0, stream>>>(embed, tab32, hscale, N);

        mean_agg_q2_kernel<<<grid, BLOCK, 0, stream>>>(tab32, hscale, idx, out, B);
    } else {
        mean_agg_kernel<<<grid, BLOCK, 0, stream>>>(embed, idx, out, B);
    }
}

// Round 8
// 470.457 us; speedup vs baseline: 1.3829x; 1.3829x over previous
//
#include <hip/hip_runtime.h>
#include <hip/hip_fp16.h>

// Mean aggregation: out[b,:] = (1/K) * sum_k embed[idx[b,k],:]
// B=100000, K=32, N=500000, D=128 fp32.
//
// R10: R8 structure (int8 table + fp16 scales via vector path) with a
// SINGLE 32-deep gather batch per wave.
// Evidence so far:
//  - R3 (512B contig loads): byte-ceiling bound, 6.3 TB/s.
//  - R6 (fp16) == R8 (int8): 3.2M single-segment random loads -> 19.4 G
//    loads/s plateau, identical time despite 2x byte difference.
//  - R9 (2 random segments per load): 5 G loads/s -- divergent-segment
//    loads cost ~4x. REVERTED.
//  - Depth correlation: 8-deep (R3) 12.2 G/s, 16-deep (R6/R8) 19.4 G/s
//    -> plateau looks MLP/latency-bound, so double depth to 32.
// This round: issue all 32 row-loads before any consumption (32 VGPRs of
// payload + acc fits the 64-VGPR/8-waves-per-SIMD budget), keeping each
// load a SINGLE random 128 B segment (64 lanes x 2 B).
// Quant pass unchanged (isolates the depth effect).

constexpr int K = 32;
constexpr int D = 128;
constexpr int WAVES_PER_BLOCK = 4;
constexpr int BLOCK = WAVES_PER_BLOCK * 64;  // 256

typedef float vfloat2 __attribute__((ext_vector_type(2)));
typedef float vfloat4 __attribute__((ext_vector_type(4)));

__device__ __forceinline__ float readlane_f32(float v, int lane) {
    union { float f; int i; } u;
    u.f = v;
    u.i = __builtin_amdgcn_readlane(u.i, lane);
    return u.f;
}

// ---------- fp32 -> int8+fp16scale conversion: 2 rows per wave ----------
__global__ __launch_bounds__(256)
void quant_kernel(const float* __restrict__ src,
                  unsigned int* __restrict__ tab32,   // packed int8 quads
                  __half* __restrict__ hscale,
                  int N) {
    const int lane = threadIdx.x & 63;
    const int sub  = lane & 31;                 // chunk within the row
    const int wid  = (blockIdx.x * BLOCK + threadIdx.x) >> 6;
    int row = wid * 2 + (lane >> 5);            // 2 rows per wave
    const bool live = row < N;
    if (row >= N) row = N - 1;                  // clamp: safe load, no store

    // Sequential 16 B/lane NT read (read-once stream; don't evict the
    // int8 table we're building).
    const vfloat4* rp = (const vfloat4*)(src + (size_t)row * D);
    vfloat4 v = __builtin_nontemporal_load(rp + sub);

    float m = fmaxf(fmaxf(fabsf(v.x), fabsf(v.y)),
                    fmaxf(fabsf(v.z), fabsf(v.w)));
#pragma unroll
    for (int off = 16; off; off >>= 1)          // reduce within 32-lane half
        m = fmaxf(m, __shfl_xor(m, off));
    m = fmaxf(m, 1e-20f);

    const float inv = 127.0f / m;
    const int qx = (int)rintf(v.x * inv);
    const int qy = (int)rintf(v.y * inv);
    const int qz = (int)rintf(v.z * inv);
    const int qw = (int)rintf(v.w * inv);
    const unsigned int pack = (unsigned)(qx & 0xff)
                            | ((unsigned)(qy & 0xff) << 8)
                            | ((unsigned)(qz & 0xff) << 16)
                            | ((unsigned)(qw & 0xff) << 24);

    if (live) {
        // int8 row = 128 B = one cache line; 32 lanes x 4 B contiguous.
        tab32[(size_t)row * (D / 4) + sub] = pack;
        if (sub == 0) hscale[row] = __float2half_rn(m * (1.0f / 127.0f));
    }
}

// ---------- int8 gather-mean, single 32-deep load batch ----------
__global__ __launch_bounds__(BLOCK, 8)
void mean_agg_q_kernel(const unsigned short* __restrict__ tab,
                       const __half* __restrict__ hscale,
                       const int* __restrict__ idx,
                       float* __restrict__ out,
                       int B) {
    const int tid  = threadIdx.x;
    const int lane = tid & 63;              // covers columns (2*lane, 2*lane+1)

    int b = blockIdx.x * WAVES_PER_BLOCK + (tid >> 6);
    b = __builtin_amdgcn_readfirstlane(b);  // wave-uniform node id
    if (b >= B) return;

    // Wave-uniform index pointer -> scalar (s_load) reads into SGPRs.
    const int* __restrict__ idx_b = idx + (size_t)b * K;
    int rows[K];
#pragma unroll
    for (int k = 0; k < K; ++k) {
        rows[k] = idx_b[k];
    }

    // All 32 per-row scales in ONE vector gather (lane k -> scale of row k;
    // lanes 32..63 mirror 0..31 so no extra lines). 1 MB fp16 table is
    // L2-hot: these line-requests don't cross the fabric.
    const int myrow = idx_b[lane & 31];
    const float s_lane = __half2float(hscale[(unsigned)myrow]);

    // Single 32-deep batch: all row-loads in flight before any use.
    // Each load: 64 lanes x 2 B = one random 128 B segment (single-segment
    // -- R9 proved divergent segments are 4x slower).
    unsigned short v[K];
#pragma unroll
    for (int j = 0; j < K; ++j) {
        v[j] = tab[(size_t)(unsigned)rows[j] * (D / 2) + lane];
    }

    float2 acc[4];
    acc[0] = acc[1] = acc[2] = acc[3] = make_float2(0.f, 0.f);

#pragma unroll
    for (int j = 0; j < K; ++j) {
        const float sj = readlane_f32(s_lane, j);   // SGPR broadcast
        const int lo = (int)(signed char)(v[j] & 0xff);
        const int hi = ((int)(short)v[j]) >> 8;
        acc[j & 3].x += sj * (float)lo;
        acc[j & 3].y += sj * (float)hi;
    }

    const float inv = 1.0f / (float)K;
    vfloat2 r;
    r.x = (acc[0].x + acc[1].x + acc[2].x + acc[3].x) * inv;
    r.y = (acc[0].y + acc[1].y + acc[2].y + acc[3].y) * inv;

    // Nontemporal: single-use output stream, don't evict table lines.
    vfloat2* op = (vfloat2*)(out + (size_t)b * D) + lane;
    __builtin_nontemporal_store(r, op);
}

// ---------- fp32 fallback (proven R3 kernel) if ws too small ----------
__global__ __launch_bounds__(BLOCK, 8)
void mean_agg_kernel(const float* __restrict__ embed,
                     const int* __restrict__ idx,
                     float* __restrict__ out,
                     int B) {
    const int tid  = threadIdx.x;
    const int lane = tid & 63;

    int b = blockIdx.x * WAVES_PER_BLOCK + (tid >> 6);
    b = __builtin_amdgcn_readfirstlane(b);
    if (b >= B) return;

    const int* __restrict__ idx_b = idx + (size_t)b * K;
    int rows[K];
#pragma unroll
    for (int k = 0; k < K; ++k) rows[k] = idx_b[k];

    float2 acc[4];
    acc[0] = acc[1] = acc[2] = acc[3] = make_float2(0.f, 0.f);

#pragma unroll
    for (int kk = 0; kk < K; kk += 8) {
        float2 v[8];
#pragma unroll
        for (int j = 0; j < 8; ++j) {
            const float2* __restrict__ rp =
                (const float2*)(embed + (size_t)(unsigned)rows[kk + j] * D);
            v[j] = rp[lane];
        }
#pragma unroll
        for (int j = 0; j < 8; ++j) {
            acc[j & 3].x += v[j].x;
            acc[j & 3].y += v[j].y;
        }
    }

    const float inv = 1.0f / (float)K;
    vfloat2 r;
    r.x = (acc[0].x + acc[1].x + acc[2].x + acc[3].x) * inv;
    r.y = (acc[0].y + acc[1].y + acc[2].y + acc[3].y) * inv;

    vfloat2* op = (vfloat2*)(out + (size_t)b * D) + lane;
    __builtin_nontemporal_store(r, op);
}

extern "C" void kernel_launch(void* const* d_in, const int* in_sizes, int n_in,
                              void* d_out, int out_size, void* d_ws, size_t ws_size,
                              hipStream_t stream) {
    const float* embed = (const float*)d_in[0];
    const int*   idx   = (const int*)d_in[1];
    float* out = (float*)d_out;

    const int B = in_sizes[1] / K;                 // in_sizes are element counts
    const size_t n_elems = (size_t)in_sizes[0];    // N * D fp32 elements
    const int N = (int)(n_elems / D);              // table rows

    // Workspace layout: [hscale: N halfs, 256B-padded][int8 table: N*D bytes]
    const size_t scale_off = 256;
    const size_t scale_bytes = ((size_t)N * sizeof(__half) + 255) & ~(size_t)255;
    const size_t tab_off = scale_off + scale_bytes;
    const size_t need = tab_off + n_elems;         // 1 byte per element

    dim3 grid((B + WAVES_PER_BLOCK - 1) / WAVES_PER_BLOCK);

    if (d_ws != nullptr && ws_size >= need) {
        __half* hscale = (__half*)((char*)d_ws + scale_off);
        unsigned int* tab32 = (unsigned int*)((char*)d_ws + tab_off);

        const int rows_per_block = WAVES_PER_BLOCK * 2;   // 2 rows per wave
        dim3 qgrid((N + rows_per_block - 1) / rows_per_block);
        quant_kernel<<<qgrid, BLOCK, 0, stream>>>(embed, tab32, hscale, N);

        mean_agg_q_kernel<<<grid, BLOCK, 0, stream>>>(
            (const unsigned short*)tab32, hscale, idx, out, B);
    } else {
        mean_agg_kernel<<<grid, BLOCK, 0, stream>>>(embed, idx, out, B);
    }
}